// Round 9
// baseline (720.011 us; speedup 1.0000x reference)
//
#include <hip/hip_runtime.h>
#include <hip/hip_bf16.h>

constexpr int N_USER = 100000;
constexpr int N_ITEM = 200000;
constexpr int N_ALL  = N_USER + N_ITEM;
constexpr int E_UI   = 3200000;
constexpr int E_UU   = 1600000;
constexpr int D      = 64;
constexpr int BLK    = 256;

// bucketing: 512 rows per bucket
constexpr int RPB_SHIFT = 9;
constexpr int RPB       = 1 << RPB_SHIFT;   // 512
constexpr int MAX_NB    = 1024;             // >= cdiv(N_ALL, RPB) = 586

// bin_scatter tile geometry
constexpr int SBLK = 512;
constexpr int EPT  = 16;
constexpr int TILE = SBLK * EPT;            // 8192 edges per block

// degree-sort
constexpr int MAXDEG = 256;                 // degrees clamp here (Poisson ~10-16, max ~40)
constexpr int RPT    = 16;                  // rows per thread in perm scatter
constexpr int PTILE  = BLK * RPT;           // 4096 rows per block

typedef __hip_bfloat16 bf16;

// ---------------- small helpers ----------------

__device__ inline int wave_incl_scan(int x, int lane) {
    #pragma unroll
    for (int off = 1; off < 64; off <<= 1) {
        int y = __shfl_up(x, off, 64);
        if (lane >= off) x += y;
    }
    return x;
}

static inline int cdiv(int a, int b) { return (a + b - 1) / b; }

// accumulate 8 bf16 (packed in an int4) into 8 f32 accumulators
__device__ inline void acc8(float* acc, const int4 v) {
    acc[0] += __int_as_float(v.x << 16);
    acc[1] += __int_as_float(v.x & 0xffff0000);
    acc[2] += __int_as_float(v.y << 16);
    acc[3] += __int_as_float(v.y & 0xffff0000);
    acc[4] += __int_as_float(v.z << 16);
    acc[5] += __int_as_float(v.z & 0xffff0000);
    acc[6] += __int_as_float(v.w << 16);
    acc[7] += __int_as_float(v.w & 0xffff0000);
}

// ---------------- init kernels (scaled bf16 emb only; sums fused into layer 1) ----------------

__global__ void init_ui_kernel(const float* __restrict__ ue,
                               const float* __restrict__ ie,
                               const float* __restrict__ rsq_out,
                               bf16* __restrict__ emb_scaled) {
    size_t t = (size_t)blockIdx.x * blockDim.x + threadIdx.x;
    const size_t total = (size_t)N_ALL * D;
    if (t >= total) return;
    const size_t userN = (size_t)N_USER * D;
    float v = (t < userN) ? ue[t] : ie[t - userN];
    int row = (int)(t >> 6);
    emb_scaled[t] = __float2bfloat16(v * rsq_out[row]);
}

__global__ void init_uu_kernel(const float* __restrict__ ue,
                               const float* __restrict__ rsq_out,
                               bf16* __restrict__ emb_scaled) {
    size_t t = (size_t)blockIdx.x * blockDim.x + threadIdx.x;
    const size_t total = (size_t)N_USER * D;
    if (t >= total) return;
    float v = ue[t];
    int row = (int)(t >> 6);
    emb_scaled[t] = __float2bfloat16(v * rsq_out[row]);
}

// ---------------- bucket histograms (both sides in one pass) ----------------

__global__ void bucket_hist2_kernel(const int* __restrict__ dst,
                                    const int* __restrict__ src, int E, int nb,
                                    int* __restrict__ bcntD_g,
                                    int* __restrict__ bcntS_g) {
    __shared__ int cD[MAX_NB];
    __shared__ int cS[MAX_NB];
    for (int b = threadIdx.x; b < nb; b += blockDim.x) { cD[b] = 0; cS[b] = 0; }
    __syncthreads();
    for (int e = blockIdx.x * blockDim.x + threadIdx.x; e < E;
         e += gridDim.x * blockDim.x) {
        atomicAdd(&cD[dst[e] >> RPB_SHIFT], 1);
        atomicAdd(&cS[src[e] >> RPB_SHIFT], 1);
    }
    __syncthreads();
    for (int b = threadIdx.x; b < nb; b += blockDim.x) {
        if (cD[b]) atomicAdd(&bcntD_g[b], cD[b]);
        if (cS[b]) atomicAdd(&bcntS_g[b], cS[b]);
    }
}

// ---------------- single-block exclusive scans ----------------

__device__ void scan_one(const int* __restrict__ cnt, int nb,
                         int* __restrict__ base, int* __restrict__ cursor,
                         int* wsum, int* carry_s) {
    int t = threadIdx.x, lane = t & 63, wid = t >> 6;
    if (t == 0) *carry_s = 0;
    for (int b0 = 0; b0 < nb; b0 += BLK) {
        __syncthreads();
        int i = b0 + t;
        int x = (i < nb) ? cnt[i] : 0;
        int s = wave_incl_scan(x, lane);
        if (lane == 63) wsum[wid] = s;
        __syncthreads();
        int add = *carry_s;
        for (int w = 0; w < wid; ++w) add += wsum[w];
        int excl = add + s - x;
        if (i < nb) { base[i] = excl; cursor[i] = excl; }
        int total = wsum[0] + wsum[1] + wsum[2] + wsum[3];
        __syncthreads();
        if (t == 0) *carry_s = add + total;  // add == old carry for t0
    }
    __syncthreads();
    if (t == 0) base[nb] = *carry_s;
    __syncthreads();
}

__global__ void scan2_buckets_kernel(const int* __restrict__ cntD, int nb,
                                     int* __restrict__ baseD, int* __restrict__ curD,
                                     const int* __restrict__ cntS,
                                     int* __restrict__ baseS, int* __restrict__ curS) {
    __shared__ int wsum[4];
    __shared__ int carry_s;
    scan_one(cntD, nb, baseD, curD, wsum, &carry_s);
    scan_one(cntS, nb, baseS, curS, wsum, &carry_s);
}

__global__ void scan_deg_kernel(const int* __restrict__ cnt, int nb,
                                int* __restrict__ base, int* __restrict__ cursor) {
    __shared__ int wsum[4];
    __shared__ int carry_s;
    scan_one(cnt, nb, base, cursor, wsum, &carry_s);
}

// ---------------- bin scatter: src IDs -> bucket-contiguous ----------------

__global__ __launch_bounds__(SBLK) void bin_scatter_src_kernel(
    const int* __restrict__ src, int E, int nb,
    int* __restrict__ cursor, int* __restrict__ binned_src) {
    __shared__ int bcnt[MAX_NB];
    __shared__ int bbase[MAX_NB];
    int t = threadIdx.x;
    for (int b = t; b < nb; b += SBLK) bcnt[b] = 0;
    __syncthreads();
    int base_e = blockIdx.x * TILE;
    int myk[EPT], myr[EPT];
    #pragma unroll
    for (int j = 0; j < EPT; ++j) {
        int e = base_e + j * SBLK + t;
        if (e < E) {
            int s = src[e];
            myk[j] = s;
            myr[j] = atomicAdd(&bcnt[s >> RPB_SHIFT], 1);
        } else {
            myk[j] = -1;
        }
    }
    __syncthreads();
    for (int b = t; b < nb; b += SBLK)
        if (bcnt[b] > 0) bbase[b] = atomicAdd(&cursor[b], bcnt[b]);
    __syncthreads();
    #pragma unroll
    for (int j = 0; j < EPT; ++j) {
        if (myk[j] >= 0)
            binned_src[bbase[myk[j] >> RPB_SHIFT] + myr[j]] = myk[j];
    }
}

// ---------------- per-bucket out-degree -> rsq_out (coalesced) ----------------

__global__ void bucket_rsq_kernel(const int* __restrict__ binned_src,
                                  const int* __restrict__ base, int n,
                                  float* __restrict__ rsq_out) {
    __shared__ int deg[RPB];
    int b = blockIdx.x;
    int row0 = b << RPB_SHIFT;
    int t = threadIdx.x;
    deg[t] = 0;
    deg[t + BLK] = 0;
    __syncthreads();
    int beg = base[b], end = base[b + 1];
    for (int e = beg + t; e < end; e += BLK)
        atomicAdd(&deg[binned_src[e] - row0], 1);
    __syncthreads();
    if (row0 + t < n)
        rsq_out[row0 + t] = 1.0f / sqrtf(fmaxf((float)deg[t], 1.0f));
    if (row0 + t + BLK < n)
        rsq_out[row0 + t + BLK] = 1.0f / sqrtf(fmaxf((float)deg[t + BLK], 1.0f));
}

// ---------------- bin scatter: edges -> bucket-contiguous (dst,src) pairs ----------------

__global__ __launch_bounds__(SBLK) void bin_scatter_kernel(
    const int* __restrict__ src, const int* __restrict__ dst, int E, int nb,
    int* __restrict__ cursor, int2* __restrict__ binned) {
    __shared__ int bcnt[MAX_NB];
    __shared__ int bbase[MAX_NB];
    int t = threadIdx.x;
    for (int b = t; b < nb; b += SBLK) bcnt[b] = 0;
    __syncthreads();
    int base_e = blockIdx.x * TILE;
    int myd[EPT], mys[EPT], myr[EPT];
    #pragma unroll
    for (int j = 0; j < EPT; ++j) {
        int e = base_e + j * SBLK + t;
        if (e < E) {
            int d = dst[e];
            mys[j] = src[e];
            myd[j] = d;
            myr[j] = atomicAdd(&bcnt[d >> RPB_SHIFT], 1);
        } else {
            myd[j] = -1;
        }
    }
    __syncthreads();
    for (int b = t; b < nb; b += SBLK)
        if (bcnt[b] > 0) bbase[b] = atomicAdd(&cursor[b], bcnt[b]);
    __syncthreads();
    #pragma unroll
    for (int j = 0; j < EPT; ++j) {
        if (myd[j] >= 0) {
            int b = myd[j] >> RPB_SHIFT;
            binned[bbase[b] + myr[j]] = make_int2(myd[j], mys[j]);
        }
    }
}

// ---------------- per-bucket CSR finalize ----------------

__global__ void bucket_csr_kernel(const int2* __restrict__ binned,
                                  const int* __restrict__ base, int nb, int n,
                                  int* __restrict__ row_ptr,
                                  float* __restrict__ rsq_in,
                                  int* __restrict__ col) {
    __shared__ int deg[RPB];
    __shared__ int cur[RPB];
    __shared__ int wsum[4];
    int b = blockIdx.x;
    int row0 = b << RPB_SHIFT;
    int nrows = min(RPB, n - row0);
    int t = threadIdx.x, lane = t & 63, wid = t >> 6;
    int beg = base[b], end = base[b + 1];

    deg[t] = 0;
    deg[t + BLK] = 0;
    __syncthreads();

    for (int e = beg + t; e < end; e += BLK)
        atomicAdd(&deg[binned[e].x - row0], 1);
    __syncthreads();

    // exclusive scan of deg[0..512) with 256 threads, two passes
    int x0 = deg[t];
    int s0 = wave_incl_scan(x0, lane);
    if (lane == 63) wsum[wid] = s0;
    __syncthreads();
    int add0 = 0;
    for (int w = 0; w < wid; ++w) add0 += wsum[w];
    int incl0 = s0 + add0;
    int tot0 = wsum[0] + wsum[1] + wsum[2] + wsum[3];
    __syncthreads();  // protect wsum before pass 2

    int x1 = deg[t + BLK];
    int s1 = wave_incl_scan(x1, lane);
    if (lane == 63) wsum[wid] = s1;
    __syncthreads();
    int add1 = 0;
    for (int w = 0; w < wid; ++w) add1 += wsum[w];
    int incl1 = s1 + add1;

    int excl0 = incl0 - x0;
    int excl1 = tot0 + incl1 - x1;
    cur[t] = beg + excl0;
    cur[t + BLK] = beg + excl1;
    if (t < nrows) {
        row_ptr[row0 + t] = beg + excl0;
        rsq_in[row0 + t] = 1.0f / sqrtf(fmaxf((float)x0, 1.0f));
    }
    if (t + BLK < nrows) {
        row_ptr[row0 + t + BLK] = beg + excl1;
        rsq_in[row0 + t + BLK] = 1.0f / sqrtf(fmaxf((float)x1, 1.0f));
    }
    if (b == nb - 1 && t == 0) row_ptr[n] = end;
    __syncthreads();

    for (int e = beg + t; e < end; e += BLK) {
        int2 p = binned[e];
        int pos = atomicAdd(&cur[p.x - row0], 1);
        col[pos] = p.y;
    }
}

// ---------------- degree-sort permutation (descending degree) ----------------
// key = (MAXDEG-1) - min(deg, MAXDEG-1)  -> ascending counting sort = descending deg

__global__ void deg_hist_kernel(const int* __restrict__ row_ptr, int n,
                                int* __restrict__ hist) {
    __shared__ int h[MAXDEG];
    for (int d = threadIdx.x; d < MAXDEG; d += blockDim.x) h[d] = 0;
    __syncthreads();
    for (int i = blockIdx.x * blockDim.x + threadIdx.x; i < n;
         i += gridDim.x * blockDim.x) {
        int deg = row_ptr[i + 1] - row_ptr[i];
        int key = (MAXDEG - 1) - min(deg, MAXDEG - 1);
        atomicAdd(&h[key], 1);
    }
    __syncthreads();
    for (int d = threadIdx.x; d < MAXDEG; d += blockDim.x)
        if (h[d]) atomicAdd(&hist[d], h[d]);
}

__global__ __launch_bounds__(BLK) void perm_scatter_kernel(
    const int* __restrict__ row_ptr, int n,
    int* __restrict__ cursor, int* __restrict__ perm) {
    __shared__ int cnt[MAXDEG];
    __shared__ int cbase[MAXDEG];
    int t = threadIdx.x;
    for (int d = t; d < MAXDEG; d += BLK) cnt[d] = 0;
    __syncthreads();
    int base_r = blockIdx.x * PTILE;
    int myk[RPT], myr[RPT];
    #pragma unroll
    for (int j = 0; j < RPT; ++j) {
        int r = base_r + j * BLK + t;
        if (r < n) {
            int deg = row_ptr[r + 1] - row_ptr[r];
            int key = (MAXDEG - 1) - min(deg, MAXDEG - 1);
            myk[j] = key;
            myr[j] = atomicAdd(&cnt[key], 1);
        } else {
            myk[j] = -1;
        }
    }
    __syncthreads();
    for (int d = t; d < MAXDEG; d += BLK)
        if (cnt[d] > 0) cbase[d] = atomicAdd(&cursor[d], cnt[d]);
    __syncthreads();
    #pragma unroll
    for (int j = 0; j < RPT; ++j) {
        if (myk[j] >= 0)
            perm[cbase[myk[j]] + myr[j]] = base_r + j * BLK + t;
    }
}

// ---------------- fused GCN layer: 8 rows/wave, 8 lanes/row, degree-sorted ----------------
// row = perm[idx]: waves process equal-degree rows (no trip-count divergence).
// Base/rsq loads hoisted before the gather loop to overlap its latency.

__global__ void gcn_layer_kernel(const int* __restrict__ perm,
                                 const int* __restrict__ row_ptr,
                                 const int* __restrict__ col,
                                 const bf16* __restrict__ emb_in,
                                 const float* __restrict__ rsq_in,
                                 const float* __restrict__ rsq_out,
                                 const float* __restrict__ baseA,
                                 const float* __restrict__ baseB,
                                 long splitElems,
                                 float* __restrict__ sum_out,
                                 bf16* __restrict__ emb_out,
                                 int n) {
    int wave = blockIdx.x * (blockDim.x >> 6) + (threadIdx.x >> 6);
    int lane = threadIdx.x & 63;
    int q = lane & 7;                  // dim chunk
    int idx = wave * 8 + (lane >> 3);  // permuted row slot
    bool act = idx < n;
    int row = act ? perm[idx] : 0;
    int beg = 0, end = 0;
    if (act) { beg = row_ptr[row]; end = row_ptr[row + 1]; }

    // hoisted epilogue inputs (overlap gather latency)
    size_t o = (size_t)row * D + (size_t)q * 8;
    float rin = act ? rsq_in[row] : 0.f;
    float ro  = (act && emb_out) ? rsq_out[row] : 0.f;
    float basev[8];
    if (act) {
        if (baseA) {
            #pragma unroll
            for (int k = 0; k < 8; ++k) {
                size_t oo = o + k;
                basev[k] = (oo < (size_t)splitElems) ? baseA[oo]
                                                     : baseB[oo - splitElems];
            }
        } else {
            const float4* sp = (const float4*)(sum_out + o);
            float4 b0 = sp[0], b1 = sp[1];
            basev[0] = b0.x; basev[1] = b0.y; basev[2] = b0.z; basev[3] = b0.w;
            basev[4] = b1.x; basev[5] = b1.y; basev[6] = b1.z; basev[7] = b1.w;
        }
    }

    float acc[8];
    #pragma unroll
    for (int k = 0; k < 8; ++k) acc[k] = 0.f;

    const int4* __restrict__ embv = (const int4*)emb_in;  // row s, chunk q at s*8+q

    int e = beg;
    for (; e + 4 <= end; e += 4) {
        int s0 = col[e];
        int s1 = col[e + 1];
        int s2 = col[e + 2];
        int s3 = col[e + 3];
        int4 w0 = embv[(size_t)s0 * 8 + q];
        int4 w1 = embv[(size_t)s1 * 8 + q];
        int4 w2 = embv[(size_t)s2 * 8 + q];
        int4 w3 = embv[(size_t)s3 * 8 + q];
        acc8(acc, w0);
        acc8(acc, w1);
        acc8(acc, w2);
        acc8(acc, w3);
    }
    for (; e < end; ++e) {
        int s0 = col[e];
        int4 w0 = embv[(size_t)s0 * 8 + q];
        acc8(acc, w0);
    }

    float vv[8];
    float ss = 0.f;
    #pragma unroll
    for (int k = 0; k < 8; ++k) {
        float v = acc[k] * rin;
        v = (v > 0.f) ? v : 0.5f * v;   // LeakyReLU(0.5)
        vv[k] = v;
        ss += v * v;
    }
    // L2-norm reduce across the 8 lanes of this row (xor within the group)
    ss += __shfl_xor(ss, 1, 64);
    ss += __shfl_xor(ss, 2, 64);
    ss += __shfl_xor(ss, 4, 64);
    float inv = 1.0f / fmaxf(sqrtf(ss), 1e-12f);

    if (act) {
        float4 o0, o1;
        o0.x = basev[0] + vv[0] * inv;
        o0.y = basev[1] + vv[1] * inv;
        o0.z = basev[2] + vv[2] * inv;
        o0.w = basev[3] + vv[3] * inv;
        o1.x = basev[4] + vv[4] * inv;
        o1.y = basev[5] + vv[5] * inv;
        o1.z = basev[6] + vv[6] * inv;
        o1.w = basev[7] + vv[7] * inv;
        float4* op = (float4*)(sum_out + o);
        op[0] = o0;
        op[1] = o1;

        if (emb_out) {
            union { int4 i4; bf16 h[8]; } pk;
            #pragma unroll
            for (int k = 0; k < 8; ++k) pk.h[k] = __float2bfloat16(vv[k] * ro);
            *(int4*)(emb_out + o) = pk.i4;
        }
    }
}

// ---------------- host side ----------------

struct GraphBufs {
    int *col, *row_ptr, *perm;
    float *rsq_out, *rsq_in;
    int *bcnt_dst, *bcnt_src, *deg_cnt;   // contiguous triple for one memset
    int *base_dst, *base_src, *cur_dst, *cur_src;
    int *deg_base, *deg_cur;
    int2 *binned;
    int *binned_src;                      // aliases first half of binned
};

static void build_graph(const int* src, const int* dst, int E, int n, int nb,
                        GraphBufs& B, hipStream_t stream) {
    (void)hipMemsetAsync(B.bcnt_dst, 0,
                         (2 * (size_t)MAX_NB + MAXDEG) * sizeof(int), stream);
    bucket_hist2_kernel<<<512, BLK, 0, stream>>>(dst, src, E, nb,
                                                 B.bcnt_dst, B.bcnt_src);
    scan2_buckets_kernel<<<1, BLK, 0, stream>>>(B.bcnt_dst, nb, B.base_dst, B.cur_dst,
                                                B.bcnt_src, B.base_src, B.cur_src);
    bin_scatter_src_kernel<<<cdiv(E, TILE), SBLK, 0, stream>>>(
        src, E, nb, B.cur_src, B.binned_src);
    bucket_rsq_kernel<<<nb, BLK, 0, stream>>>(B.binned_src, B.base_src, n, B.rsq_out);
    bin_scatter_kernel<<<cdiv(E, TILE), SBLK, 0, stream>>>(
        src, dst, E, nb, B.cur_dst, B.binned);
    bucket_csr_kernel<<<nb, BLK, 0, stream>>>(B.binned, B.base_dst, nb, n,
                                              B.row_ptr, B.rsq_in, B.col);
    // degree-sorted permutation (descending)
    deg_hist_kernel<<<256, BLK, 0, stream>>>(B.row_ptr, n, B.deg_cnt);
    scan_deg_kernel<<<1, BLK, 0, stream>>>(B.deg_cnt, MAXDEG, B.deg_base, B.deg_cur);
    perm_scatter_kernel<<<cdiv(n, PTILE), BLK, 0, stream>>>(B.row_ptr, n,
                                                            B.deg_cur, B.perm);
}

extern "C" void kernel_launch(void* const* d_in, const int* in_sizes, int n_in,
                              void* d_out, int out_size, void* d_ws, size_t ws_size,
                              hipStream_t stream) {
    const float* user_emb = (const float*)d_in[0];
    const float* item_emb = (const float*)d_in[1];
    const int*   ui_src   = (const int*)d_in[2];
    const int*   ui_dst   = (const int*)d_in[3];
    const int*   uu_src   = (const int*)d_in[4];
    const int*   uu_dst   = (const int*)d_in[5];

    float* out    = (float*)d_out;
    float* ui_sum = out;                          // [N_ALL * D]
    float* uu_sum = out + (size_t)N_ALL * D;      // [N_USER * D]

    const int NB_UI = cdiv(N_ALL, RPB);   // 586
    const int NB_UU = cdiv(N_USER, RPB);  // 196

    // ws layout: embA | embB | binned (E_UI int2) | UU scratch | bucket/deg arrays
    char* wp = (char*)d_ws;
    bf16* embA = (bf16*)wp;  wp += (size_t)N_ALL * D * sizeof(bf16);   // 38.4 MB
    bf16* embB = (bf16*)wp;  wp += (size_t)N_ALL * D * sizeof(bf16);   // 38.4 MB
    int2* binned = (int2*)wp; wp += (size_t)E_UI * sizeof(int2);       // 25.6 MB
    // UU scratch (used only in UU phase)
    int*   uu_col     = (int*)wp;   wp += (size_t)E_UU * sizeof(int);        // 6.4 MB
    int*   uu_row_ptr = (int*)wp;   wp += (size_t)(N_USER + 1) * sizeof(int);
    float* uu_rsq_out = (float*)wp; wp += (size_t)N_USER * sizeof(float);
    float* uu_rsq_in  = (float*)wp; wp += (size_t)N_USER * sizeof(float);
    int*   uu_perm    = (int*)wp;   wp += (size_t)N_USER * sizeof(int);
    // shared small bucket/deg arrays (bcnt_dst, bcnt_src, deg_cnt contiguous!)
    int* bcnt_dst = (int*)wp;  wp += (size_t)MAX_NB * sizeof(int);
    int* bcnt_src = (int*)wp;  wp += (size_t)MAX_NB * sizeof(int);
    int* deg_cnt  = (int*)wp;  wp += (size_t)MAXDEG * sizeof(int);
    int* base_dst = (int*)wp;  wp += (size_t)(MAX_NB + 1) * sizeof(int);
    int* base_src = (int*)wp;  wp += (size_t)(MAX_NB + 1) * sizeof(int);
    int* cur_dst  = (int*)wp;  wp += (size_t)MAX_NB * sizeof(int);
    int* cur_src  = (int*)wp;  wp += (size_t)MAX_NB * sizeof(int);
    int* deg_base = (int*)wp;  wp += (size_t)(MAXDEG + 1) * sizeof(int);
    int* deg_cur  = (int*)wp;  wp += (size_t)MAXDEG * sizeof(int);

    const int ROWS_PER_BLK = (BLK / 64) * 8;  // 32

    // ---------------- user-item graph ----------------
    {
        // UI CSR scratch lives in the uu_sum region of d_out (dead during UI phase).
        char* p = (char*)uu_sum;
        GraphBufs UI;
        UI.col      = (int*)p;   p += (size_t)E_UI * sizeof(int);          // 12.8 MB
        UI.row_ptr  = (int*)p;   p += (size_t)(N_ALL + 1) * sizeof(int);   // 1.2 MB
        UI.rsq_out  = (float*)p; p += (size_t)N_ALL * sizeof(float);       // 1.2 MB
        UI.rsq_in   = (float*)p; p += (size_t)N_ALL * sizeof(float);       // 1.2 MB
        UI.perm     = (int*)p;   p += (size_t)N_ALL * sizeof(int);         // 1.2 MB
        UI.bcnt_dst = bcnt_dst; UI.bcnt_src = bcnt_src; UI.deg_cnt = deg_cnt;
        UI.base_dst = base_dst; UI.base_src = base_src;
        UI.cur_dst  = cur_dst;  UI.cur_src  = cur_src;
        UI.deg_base = deg_base; UI.deg_cur = deg_cur;
        UI.binned = binned;
        UI.binned_src = (int*)binned;   // alias: dead before bin_scatter(dst) runs

        build_graph(ui_src, ui_dst, E_UI, N_ALL, NB_UI, UI, stream);

        size_t tot = (size_t)N_ALL * D;
        init_ui_kernel<<<cdiv((int)tot, BLK), BLK, 0, stream>>>(
            user_emb, item_emb, UI.rsq_out, embA);

        bf16* bufs[2] = {embA, embB};
        for (int l = 0; l < 3; ++l) {
            const float* bA = (l == 0) ? user_emb : nullptr;
            const float* bB = (l == 0) ? item_emb : nullptr;
            bf16* eout = (l == 2) ? nullptr : bufs[(l + 1) & 1];
            gcn_layer_kernel<<<cdiv(N_ALL, ROWS_PER_BLK), BLK, 0, stream>>>(
                UI.perm, UI.row_ptr, UI.col, bufs[l & 1], UI.rsq_in, UI.rsq_out,
                bA, bB, (long)N_USER * D,
                ui_sum, eout, N_ALL);
        }
    }

    // ---------------- user-user graph ----------------
    {
        GraphBufs UU;
        UU.col = uu_col;
        UU.row_ptr = uu_row_ptr;
        UU.rsq_out = uu_rsq_out;
        UU.rsq_in = uu_rsq_in;
        UU.perm = uu_perm;
        UU.bcnt_dst = bcnt_dst; UU.bcnt_src = bcnt_src; UU.deg_cnt = deg_cnt;
        UU.base_dst = base_dst; UU.base_src = base_src;
        UU.cur_dst  = cur_dst;  UU.cur_src  = cur_src;
        UU.deg_base = deg_base; UU.deg_cur = deg_cur;
        UU.binned = binned;             // reuse (only first E_UU entries)
        UU.binned_src = (int*)binned;

        build_graph(uu_src, uu_dst, E_UU, N_USER, NB_UU, UU, stream);

        size_t tot = (size_t)N_USER * D;
        init_uu_kernel<<<cdiv((int)tot, BLK), BLK, 0, stream>>>(
            user_emb, UU.rsq_out, embA);

        bf16* bufs[2] = {embA, embB};
        for (int l = 0; l < 2; ++l) {
            const float* bA = (l == 0) ? user_emb : nullptr;
            bf16* eout = (l == 1) ? nullptr : bufs[(l + 1) & 1];
            gcn_layer_kernel<<<cdiv(N_USER, ROWS_PER_BLK), BLK, 0, stream>>>(
                UU.perm, UU.row_ptr, UU.col, bufs[l & 1], UU.rsq_in, UU.rsq_out,
                bA, nullptr, (long)N_USER * D,
                uu_sum, eout, N_USER);
        }
    }
}

// Round 10
// 648.071 us; speedup vs baseline: 1.1110x; 1.1110x over previous
//
#include <hip/hip_runtime.h>
#include <hip/hip_bf16.h>

constexpr int N_USER = 100000;
constexpr int N_ITEM = 200000;
constexpr int N_ALL  = N_USER + N_ITEM;
constexpr int E_UI   = 3200000;
constexpr int E_UU   = 1600000;
constexpr int D      = 64;
constexpr int BLK    = 256;

// bucketing: 512 rows per bucket
constexpr int RPB_SHIFT = 9;
constexpr int RPB       = 1 << RPB_SHIFT;   // 512
constexpr int MAX_NB    = 1024;             // >= cdiv(N_ALL, RPB) = 586

// merged bin_scatter tile geometry (EPT=8 to keep VGPRs moderate: 4 arrays x 8)
constexpr int SBLK = 512;
constexpr int EPT  = 8;
constexpr int TILE = SBLK * EPT;            // 4096 edges per block

typedef __hip_bfloat16 bf16;
typedef float f32x4 __attribute__((ext_vector_type(4)));
typedef int   i32x4 __attribute__((ext_vector_type(4)));

// ---------------- small helpers ----------------

__device__ inline int wave_incl_scan(int x, int lane) {
    #pragma unroll
    for (int off = 1; off < 64; off <<= 1) {
        int y = __shfl_up(x, off, 64);
        if (lane >= off) x += y;
    }
    return x;
}

static inline int cdiv(int a, int b) { return (a + b - 1) / b; }

// accumulate 8 bf16 (packed in an int4) into 8 f32 accumulators
__device__ inline void acc8(float* acc, const int4 v) {
    acc[0] += __int_as_float(v.x << 16);
    acc[1] += __int_as_float(v.x & 0xffff0000);
    acc[2] += __int_as_float(v.y << 16);
    acc[3] += __int_as_float(v.y & 0xffff0000);
    acc[4] += __int_as_float(v.z << 16);
    acc[5] += __int_as_float(v.z & 0xffff0000);
    acc[6] += __int_as_float(v.w << 16);
    acc[7] += __int_as_float(v.w & 0xffff0000);
}

// ---------------- init kernels (scaled bf16 emb only; sums fused into layer 1) ----------------

__global__ void init_ui_kernel(const float* __restrict__ ue,
                               const float* __restrict__ ie,
                               const float* __restrict__ rsq_out,
                               bf16* __restrict__ emb_scaled) {
    size_t t = (size_t)blockIdx.x * blockDim.x + threadIdx.x;
    const size_t total = (size_t)N_ALL * D;
    if (t >= total) return;
    const size_t userN = (size_t)N_USER * D;
    float v = (t < userN) ? ue[t] : ie[t - userN];
    int row = (int)(t >> 6);
    emb_scaled[t] = __float2bfloat16(v * rsq_out[row]);
}

__global__ void init_uu_kernel(const float* __restrict__ ue,
                               const float* __restrict__ rsq_out,
                               bf16* __restrict__ emb_scaled) {
    size_t t = (size_t)blockIdx.x * blockDim.x + threadIdx.x;
    const size_t total = (size_t)N_USER * D;
    if (t >= total) return;
    float v = ue[t];
    int row = (int)(t >> 6);
    emb_scaled[t] = __float2bfloat16(v * rsq_out[row]);
}

// ---------------- bucket histograms (both sides in one pass) ----------------

__global__ void bucket_hist2_kernel(const int* __restrict__ dst,
                                    const int* __restrict__ src, int E, int nb,
                                    int* __restrict__ bcntD_g,
                                    int* __restrict__ bcntS_g) {
    __shared__ int cD[MAX_NB];
    __shared__ int cS[MAX_NB];
    for (int b = threadIdx.x; b < nb; b += blockDim.x) { cD[b] = 0; cS[b] = 0; }
    __syncthreads();
    for (int e = blockIdx.x * blockDim.x + threadIdx.x; e < E;
         e += gridDim.x * blockDim.x) {
        atomicAdd(&cD[dst[e] >> RPB_SHIFT], 1);
        atomicAdd(&cS[src[e] >> RPB_SHIFT], 1);
    }
    __syncthreads();
    for (int b = threadIdx.x; b < nb; b += blockDim.x) {
        if (cD[b]) atomicAdd(&bcntD_g[b], cD[b]);
        if (cS[b]) atomicAdd(&bcntS_g[b], cS[b]);
    }
}

// ---------------- single-block exclusive scans (dst + src in one launch) ----------------

__device__ void scan_one(const int* __restrict__ cnt, int nb,
                         int* __restrict__ base, int* __restrict__ cursor,
                         int* wsum, int* carry_s) {
    int t = threadIdx.x, lane = t & 63, wid = t >> 6;
    if (t == 0) *carry_s = 0;
    for (int b0 = 0; b0 < nb; b0 += BLK) {
        __syncthreads();
        int i = b0 + t;
        int x = (i < nb) ? cnt[i] : 0;
        int s = wave_incl_scan(x, lane);
        if (lane == 63) wsum[wid] = s;
        __syncthreads();
        int add = *carry_s;
        for (int w = 0; w < wid; ++w) add += wsum[w];
        int excl = add + s - x;
        if (i < nb) { base[i] = excl; cursor[i] = excl; }
        int total = wsum[0] + wsum[1] + wsum[2] + wsum[3];
        __syncthreads();
        if (t == 0) *carry_s = add + total;  // add == old carry for t0
    }
    __syncthreads();
    if (t == 0) base[nb] = *carry_s;
    __syncthreads();
}

__global__ void scan2_buckets_kernel(const int* __restrict__ cntD, int nb,
                                     int* __restrict__ baseD, int* __restrict__ curD,
                                     const int* __restrict__ cntS,
                                     int* __restrict__ baseS, int* __restrict__ curS) {
    __shared__ int wsum[4];
    __shared__ int carry_s;
    scan_one(cntD, nb, baseD, curD, wsum, &carry_s);
    scan_one(cntS, nb, baseS, curS, wsum, &carry_s);
}

// ---------------- merged bin scatter: both sides in one edge pass ----------------

__global__ __launch_bounds__(SBLK) void bin_scatter2_kernel(
    const int* __restrict__ src, const int* __restrict__ dst, int E, int nb,
    int* __restrict__ curS, int* __restrict__ curD,
    int* __restrict__ binned_src, int2* __restrict__ binned) {
    __shared__ int cS[MAX_NB];
    __shared__ int bS[MAX_NB];
    __shared__ int cD[MAX_NB];
    __shared__ int bD[MAX_NB];
    int t = threadIdx.x;
    for (int b = t; b < nb; b += SBLK) { cS[b] = 0; cD[b] = 0; }
    __syncthreads();
    int base_e = blockIdx.x * TILE;
    int mys[EPT], myd[EPT], myrS[EPT], myrD[EPT];
    #pragma unroll
    for (int j = 0; j < EPT; ++j) {
        int e = base_e + j * SBLK + t;
        if (e < E) {
            int s = src[e];
            int d = dst[e];
            mys[j] = s;
            myd[j] = d;
            myrS[j] = atomicAdd(&cS[s >> RPB_SHIFT], 1);
            myrD[j] = atomicAdd(&cD[d >> RPB_SHIFT], 1);
        } else {
            myd[j] = -1;
        }
    }
    __syncthreads();
    for (int b = t; b < nb; b += SBLK) {
        if (cS[b] > 0) bS[b] = atomicAdd(&curS[b], cS[b]);
        if (cD[b] > 0) bD[b] = atomicAdd(&curD[b], cD[b]);
    }
    __syncthreads();
    #pragma unroll
    for (int j = 0; j < EPT; ++j) {
        if (myd[j] >= 0) {
            binned_src[bS[mys[j] >> RPB_SHIFT] + myrS[j]] = mys[j];
            binned[bD[myd[j] >> RPB_SHIFT] + myrD[j]] = make_int2(myd[j], mys[j]);
        }
    }
}

// ---------------- merged per-bucket finalize ----------------
// blocks [0, nb): dst-side CSR (row_ptr, rsq_in, col)
// blocks [nb, 2nb): src-side degree -> rsq_out

__global__ void bucket_finalize_kernel(const int2* __restrict__ binned,
                                       const int* __restrict__ baseD,
                                       const int* __restrict__ binned_src,
                                       const int* __restrict__ baseS,
                                       int nb, int n,
                                       int* __restrict__ row_ptr,
                                       float* __restrict__ rsq_in,
                                       int* __restrict__ col,
                                       float* __restrict__ rsq_out) {
    __shared__ int deg[RPB];
    __shared__ int cur[RPB];
    __shared__ int wsum[4];
    int bb = blockIdx.x;
    int t = threadIdx.x, lane = t & 63, wid = t >> 6;

    if (bb >= nb) {
        // ---- src side: out-degree -> rsq_out ----
        int b = bb - nb;
        int row0 = b << RPB_SHIFT;
        deg[t] = 0;
        deg[t + BLK] = 0;
        __syncthreads();
        int beg = baseS[b], end = baseS[b + 1];
        for (int e = beg + t; e < end; e += BLK)
            atomicAdd(&deg[binned_src[e] - row0], 1);
        __syncthreads();
        if (row0 + t < n)
            rsq_out[row0 + t] = 1.0f / sqrtf(fmaxf((float)deg[t], 1.0f));
        if (row0 + t + BLK < n)
            rsq_out[row0 + t + BLK] = 1.0f / sqrtf(fmaxf((float)deg[t + BLK], 1.0f));
        return;
    }

    // ---- dst side: CSR ----
    int b = bb;
    int row0 = b << RPB_SHIFT;
    int nrows = min(RPB, n - row0);
    int beg = baseD[b], end = baseD[b + 1];

    deg[t] = 0;
    deg[t + BLK] = 0;
    __syncthreads();

    for (int e = beg + t; e < end; e += BLK)
        atomicAdd(&deg[binned[e].x - row0], 1);
    __syncthreads();

    // exclusive scan of deg[0..512) with 256 threads, two passes
    int x0 = deg[t];
    int s0 = wave_incl_scan(x0, lane);
    if (lane == 63) wsum[wid] = s0;
    __syncthreads();
    int add0 = 0;
    for (int w = 0; w < wid; ++w) add0 += wsum[w];
    int incl0 = s0 + add0;
    int tot0 = wsum[0] + wsum[1] + wsum[2] + wsum[3];
    __syncthreads();  // protect wsum before pass 2

    int x1 = deg[t + BLK];
    int s1 = wave_incl_scan(x1, lane);
    if (lane == 63) wsum[wid] = s1;
    __syncthreads();
    int add1 = 0;
    for (int w = 0; w < wid; ++w) add1 += wsum[w];
    int incl1 = s1 + add1;

    int excl0 = incl0 - x0;
    int excl1 = tot0 + incl1 - x1;
    cur[t] = beg + excl0;
    cur[t + BLK] = beg + excl1;
    if (t < nrows) {
        row_ptr[row0 + t] = beg + excl0;
        rsq_in[row0 + t] = 1.0f / sqrtf(fmaxf((float)x0, 1.0f));
    }
    if (t + BLK < nrows) {
        row_ptr[row0 + t + BLK] = beg + excl1;
        rsq_in[row0 + t + BLK] = 1.0f / sqrtf(fmaxf((float)x1, 1.0f));
    }
    if (b == nb - 1 && t == 0) row_ptr[n] = end;
    __syncthreads();

    for (int e = beg + t; e < end; e += BLK) {
        int2 p = binned[e];
        int pos = atomicAdd(&cur[p.x - row0], 1);
        col[pos] = p.y;
    }
}

// ---------------- fused GCN layer: 8 rows/wave, 8 lanes/row ----------------
// Hoisted epilogue inputs (base/rsq loads overlap gather latency).
// Non-temporal loads/stores on all streaming (zero-reuse) traffic so the L2
// keeps the bf16 gather table instead.
// emb_out == nullptr on the final layer of each graph (output never read).

__global__ void gcn_layer_kernel(const int* __restrict__ row_ptr,
                                 const int* __restrict__ col,
                                 const bf16* __restrict__ emb_in,
                                 const float* __restrict__ rsq_in,
                                 const float* __restrict__ rsq_out,
                                 const float* __restrict__ baseA,
                                 const float* __restrict__ baseB,
                                 long splitElems,
                                 float* __restrict__ sum_out,
                                 bf16* __restrict__ emb_out,
                                 int n) {
    int wave = blockIdx.x * (blockDim.x >> 6) + (threadIdx.x >> 6);
    int lane = threadIdx.x & 63;
    int q = lane & 7;                 // dim chunk
    int row = wave * 8 + (lane >> 3); // row slot
    bool act = row < n;
    int beg = 0, end = 0;
    if (act) { beg = row_ptr[row]; end = row_ptr[row + 1]; }

    // hoisted epilogue inputs (overlap gather latency); nt: no reuse
    size_t o = (size_t)row * D + (size_t)q * 8;
    float rin = act ? rsq_in[row] : 0.f;
    float ro  = (act && emb_out) ? rsq_out[row] : 0.f;
    f32x4 b0 = {0.f, 0.f, 0.f, 0.f}, b1 = {0.f, 0.f, 0.f, 0.f};
    if (act) {
        const f32x4* sp;
        if (baseA) {
            // whole row lies in exactly one of baseA/baseB (split at row granularity)
            const float* bsrc = ((size_t)row * D < (size_t)splitElems)
                                    ? (baseA + o) : (baseB + (o - splitElems));
            sp = (const f32x4*)bsrc;
        } else {
            sp = (const f32x4*)(sum_out + o);
        }
        b0 = __builtin_nontemporal_load(sp);
        b1 = __builtin_nontemporal_load(sp + 1);
    }

    float acc[8];
    #pragma unroll
    for (int k = 0; k < 8; ++k) acc[k] = 0.f;

    const int4* __restrict__ embv = (const int4*)emb_in;  // row s, chunk q at s*8+q

    int e = beg;
    for (; e + 4 <= end; e += 4) {
        int s0 = col[e];
        int s1 = col[e + 1];
        int s2 = col[e + 2];
        int s3 = col[e + 3];
        int4 w0 = embv[(size_t)s0 * 8 + q];
        int4 w1 = embv[(size_t)s1 * 8 + q];
        int4 w2 = embv[(size_t)s2 * 8 + q];
        int4 w3 = embv[(size_t)s3 * 8 + q];
        acc8(acc, w0);
        acc8(acc, w1);
        acc8(acc, w2);
        acc8(acc, w3);
    }
    for (; e < end; ++e) {
        int s0 = col[e];
        int4 w0 = embv[(size_t)s0 * 8 + q];
        acc8(acc, w0);
    }

    float vv[8];
    float ss = 0.f;
    #pragma unroll
    for (int k = 0; k < 8; ++k) {
        float v = acc[k] * rin;
        v = (v > 0.f) ? v : 0.5f * v;   // LeakyReLU(0.5)
        vv[k] = v;
        ss += v * v;
    }
    // L2-norm reduce across the 8 lanes of this row (xor within the group)
    ss += __shfl_xor(ss, 1, 64);
    ss += __shfl_xor(ss, 2, 64);
    ss += __shfl_xor(ss, 4, 64);
    float inv = 1.0f / fmaxf(sqrtf(ss), 1e-12f);

    if (act) {
        f32x4 o0, o1;
        o0.x = b0.x + vv[0] * inv;
        o0.y = b0.y + vv[1] * inv;
        o0.z = b0.z + vv[2] * inv;
        o0.w = b0.w + vv[3] * inv;
        o1.x = b1.x + vv[4] * inv;
        o1.y = b1.y + vv[5] * inv;
        o1.z = b1.z + vv[6] * inv;
        o1.w = b1.w + vv[7] * inv;
        f32x4* op = (f32x4*)(sum_out + o);
        __builtin_nontemporal_store(o0, op);
        __builtin_nontemporal_store(o1, op + 1);

        if (emb_out) {
            union { i32x4 i4; bf16 h[8]; } pk;
            #pragma unroll
            for (int k = 0; k < 8; ++k) pk.h[k] = __float2bfloat16(vv[k] * ro);
            __builtin_nontemporal_store(pk.i4, (i32x4*)(emb_out + o));
        }
    }
}

// ---------------- host side ----------------

struct GraphBufs {
    int *col, *row_ptr;
    float *rsq_out, *rsq_in;
    int *bcnt_dst, *bcnt_src;           // contiguous pair for one memset
    int *base_dst, *base_src, *cur_dst, *cur_src;
    int2 *binned;
    int *binned_src;
};

static void build_graph(const int* src, const int* dst, int E, int n, int nb,
                        GraphBufs& B, hipStream_t stream) {
    (void)hipMemsetAsync(B.bcnt_dst, 0, 2 * (size_t)MAX_NB * sizeof(int), stream);
    bucket_hist2_kernel<<<512, BLK, 0, stream>>>(dst, src, E, nb,
                                                 B.bcnt_dst, B.bcnt_src);
    scan2_buckets_kernel<<<1, BLK, 0, stream>>>(B.bcnt_dst, nb, B.base_dst, B.cur_dst,
                                                B.bcnt_src, B.base_src, B.cur_src);
    bin_scatter2_kernel<<<cdiv(E, TILE), SBLK, 0, stream>>>(
        src, dst, E, nb, B.cur_src, B.cur_dst, B.binned_src, B.binned);
    bucket_finalize_kernel<<<2 * nb, BLK, 0, stream>>>(
        B.binned, B.base_dst, B.binned_src, B.base_src, nb, n,
        B.row_ptr, B.rsq_in, B.col, B.rsq_out);
}

extern "C" void kernel_launch(void* const* d_in, const int* in_sizes, int n_in,
                              void* d_out, int out_size, void* d_ws, size_t ws_size,
                              hipStream_t stream) {
    const float* user_emb = (const float*)d_in[0];
    const float* item_emb = (const float*)d_in[1];
    const int*   ui_src   = (const int*)d_in[2];
    const int*   ui_dst   = (const int*)d_in[3];
    const int*   uu_src   = (const int*)d_in[4];
    const int*   uu_dst   = (const int*)d_in[5];

    float* out    = (float*)d_out;
    float* ui_sum = out;                          // [N_ALL * D]
    float* uu_sum = out + (size_t)N_ALL * D;      // [N_USER * D]

    const int NB_UI = cdiv(N_ALL, RPB);   // 586
    const int NB_UU = cdiv(N_USER, RPB);  // 196

    // ws layout: embA | embB | binned (E_UI int2) | binned_src (E_UI int) |
    //            UU scratch | bucket arrays
    char* wp = (char*)d_ws;
    bf16* embA = (bf16*)wp;  wp += (size_t)N_ALL * D * sizeof(bf16);   // 38.4 MB
    bf16* embB = (bf16*)wp;  wp += (size_t)N_ALL * D * sizeof(bf16);   // 38.4 MB
    int2* binned = (int2*)wp; wp += (size_t)E_UI * sizeof(int2);       // 25.6 MB
    int* binned_src = (int*)wp; wp += (size_t)E_UI * sizeof(int);      // 12.8 MB
    // UU scratch (used only in UU phase)
    int*   uu_col     = (int*)wp;   wp += (size_t)E_UU * sizeof(int);        // 6.4 MB
    int*   uu_row_ptr = (int*)wp;   wp += (size_t)(N_USER + 1) * sizeof(int);
    float* uu_rsq_out = (float*)wp; wp += (size_t)N_USER * sizeof(float);
    float* uu_rsq_in  = (float*)wp; wp += (size_t)N_USER * sizeof(float);
    // shared small bucket arrays (bcnt_dst, bcnt_src contiguous for one memset)
    int* bcnt_dst = (int*)wp;  wp += (size_t)MAX_NB * sizeof(int);
    int* bcnt_src = (int*)wp;  wp += (size_t)MAX_NB * sizeof(int);
    int* base_dst = (int*)wp;  wp += (size_t)(MAX_NB + 1) * sizeof(int);
    int* base_src = (int*)wp;  wp += (size_t)(MAX_NB + 1) * sizeof(int);
    int* cur_dst  = (int*)wp;  wp += (size_t)MAX_NB * sizeof(int);
    int* cur_src  = (int*)wp;  wp += (size_t)MAX_NB * sizeof(int);

    const int ROWS_PER_BLK = (BLK / 64) * 8;  // 32

    // ---------------- user-item graph ----------------
    {
        // UI CSR scratch lives in the uu_sum region of d_out (dead during UI phase).
        char* p = (char*)uu_sum;
        GraphBufs UI;
        UI.col      = (int*)p;   p += (size_t)E_UI * sizeof(int);          // 12.8 MB
        UI.row_ptr  = (int*)p;   p += (size_t)(N_ALL + 1) * sizeof(int);   // 1.2 MB
        UI.rsq_out  = (float*)p; p += (size_t)N_ALL * sizeof(float);       // 1.2 MB
        UI.rsq_in   = (float*)p; p += (size_t)N_ALL * sizeof(float);       // 1.2 MB
        UI.bcnt_dst = bcnt_dst; UI.bcnt_src = bcnt_src;
        UI.base_dst = base_dst; UI.base_src = base_src;
        UI.cur_dst  = cur_dst;  UI.cur_src  = cur_src;
        UI.binned = binned;
        UI.binned_src = binned_src;

        build_graph(ui_src, ui_dst, E_UI, N_ALL, NB_UI, UI, stream);

        size_t tot = (size_t)N_ALL * D;
        init_ui_kernel<<<cdiv((int)tot, BLK), BLK, 0, stream>>>(
            user_emb, item_emb, UI.rsq_out, embA);

        bf16* bufs[2] = {embA, embB};
        for (int l = 0; l < 3; ++l) {
            const float* bA = (l == 0) ? user_emb : nullptr;
            const float* bB = (l == 0) ? item_emb : nullptr;
            bf16* eout = (l == 2) ? nullptr : bufs[(l + 1) & 1];
            gcn_layer_kernel<<<cdiv(N_ALL, ROWS_PER_BLK), BLK, 0, stream>>>(
                UI.row_ptr, UI.col, bufs[l & 1], UI.rsq_in, UI.rsq_out,
                bA, bB, (long)N_USER * D,
                ui_sum, eout, N_ALL);
        }
    }

    // ---------------- user-user graph ----------------
    {
        GraphBufs UU;
        UU.col = uu_col;
        UU.row_ptr = uu_row_ptr;
        UU.rsq_out = uu_rsq_out;
        UU.rsq_in = uu_rsq_in;
        UU.bcnt_dst = bcnt_dst; UU.bcnt_src = bcnt_src;
        UU.base_dst = base_dst; UU.base_src = base_src;
        UU.cur_dst  = cur_dst;  UU.cur_src  = cur_src;
        UU.binned = binned;             // reuse (only first E_UU entries)
        UU.binned_src = binned_src;

        build_graph(uu_src, uu_dst, E_UU, N_USER, NB_UU, UU, stream);

        size_t tot = (size_t)N_USER * D;
        init_uu_kernel<<<cdiv((int)tot, BLK), BLK, 0, stream>>>(
            user_emb, UU.rsq_out, embA);

        bf16* bufs[2] = {embA, embB};
        for (int l = 0; l < 2; ++l) {
            const float* bA = (l == 0) ? user_emb : nullptr;
            bf16* eout = (l == 1) ? nullptr : bufs[(l + 1) & 1];
            gcn_layer_kernel<<<cdiv(N_USER, ROWS_PER_BLK), BLK, 0, stream>>>(
                UU.row_ptr, UU.col, bufs[l & 1], UU.rsq_in, UU.rsq_out,
                bA, nullptr, (long)N_USER * D,
                uu_sum, eout, N_USER);
        }
    }
}